// Round 1
// baseline (289.446 us; speedup 1.0000x reference)
//
#include <hip/hip_runtime.h>
#include <hip/hip_bf16.h>

#define HW 1024
#define C_CH 768
#define BATCH 16
#define NG 32
#define CPG 24
#define EPS 1e-5f

typedef __attribute__((ext_vector_type(8))) short bf16x8;
typedef __attribute__((ext_vector_type(4))) float f32x4;
typedef unsigned short u16;
typedef unsigned int u32;

typedef const __attribute__((address_space(1))) void* gas_ptr;
typedef __attribute__((address_space(3))) void* las_ptr;

__device__ __forceinline__ void load_lds16(const void* g, void* l) {
    __builtin_amdgcn_global_load_lds((gas_ptr)g, (las_ptr)l, 16, 0, 0);
}

__device__ __forceinline__ u16 f2bf(float f) {
    __hip_bfloat16 h = __float2bfloat16(f);
    return *(u16*)&h;
}
__device__ __forceinline__ float bf2f(u16 u) {
    return __uint_as_float(((u32)u) << 16);
}

// ---------------- cast f32 -> bf16 (vectorized x4) ----------------
__global__ __launch_bounds__(256) void cast_bf16_kernel(const float4* __restrict__ in,
                                                        ushort4* __restrict__ out, int n4) {
    int i = blockIdx.x * 256 + threadIdx.x;
    if (i >= n4) return;
    float4 v = in[i];
    ushort4 u;
    u.x = f2bf(v.x); u.y = f2bf(v.y); u.z = f2bf(v.z); u.w = f2bf(v.w);
    out[i] = u;
}

// ---------------- GroupNorm stats: one block per (b,g) ----------------
__global__ __launch_bounds__(256) void gn_stats_kernel(const float* __restrict__ x,
                                                       float* __restrict__ stats) {
    int bg = blockIdx.x;                       // b*NG + g
    const float4* p4 = (const float4*)(x + (size_t)bg * (CPG * HW));
    float s = 0.f, s2 = 0.f;
    for (int i = threadIdx.x; i < (CPG * HW) / 4; i += 256) {
        float4 v = p4[i];
        s  += v.x + v.y + v.z + v.w;
        s2 += v.x * v.x + v.y * v.y + v.z * v.z + v.w * v.w;
    }
    int lane = threadIdx.x & 63, wid = threadIdx.x >> 6;
    for (int off = 32; off; off >>= 1) {
        s  += __shfl_xor(s,  off, 64);
        s2 += __shfl_xor(s2, off, 64);
    }
    __shared__ float red[8];
    if (lane == 0) { red[wid * 2] = s; red[wid * 2 + 1] = s2; }
    __syncthreads();
    if (threadIdx.x == 0) {
        s = red[0] + red[2] + red[4] + red[6];
        s2 = red[1] + red[3] + red[5] + red[7];
        float mean = s / (float)(CPG * HW);
        float var  = s2 / (float)(CPG * HW) - mean * mean;
        stats[2 * bg]     = mean;
        stats[2 * bg + 1] = rsqrtf(var + EPS);
    }
}

// ------------- GroupNorm normalize + transpose -> xn_T [B, HW, C] bf16 -------------
__global__ __launch_bounds__(256) void gn_norm_kernel(const float* __restrict__ x,
                                                      const float* __restrict__ stats,
                                                      const float* __restrict__ gamma,
                                                      const float* __restrict__ beta,
                                                      __hip_bfloat16* __restrict__ xnT) {
    __shared__ float lds[64][65];
    int b  = blockIdx.y;
    int p0 = blockIdx.x * 64;
    int t = threadIdx.x;
    int lane = t & 63;
    int grp  = t >> 6;   // 0..3
    for (int cc = 0; cc < C_CH / 64; cc++) {
        int c0 = cc * 64;
        for (int i = 0; i < 16; i++) {
            int c = c0 + grp * 16 + i;
            float2 st = ((const float2*)stats)[b * NG + c / CPG];
            float ga = gamma[c], be = beta[c];
            float v = x[((size_t)b * C_CH + c) * HW + p0 + lane];
            lds[lane][grp * 16 + i] = (v - st.x) * st.y * ga + be;
        }
        __syncthreads();
        for (int i = 0; i < 16; i++) {
            int pp = grp * 16 + i;
            xnT[((size_t)b * HW + p0 + pp) * C_CH + c0 + lane] =
                __float2bfloat16(lds[pp][lane]);
        }
        __syncthreads();
    }
}

// ---------------- row softmax over att [rows][768] bf16, in place ----------------
__global__ __launch_bounds__(256) void softmax_kernel(__hip_bfloat16* __restrict__ att) {
    int row  = blockIdx.x * 4 + (threadIdx.x >> 6);
    int lane = threadIdx.x & 63;
    u16* p = (u16*)(att + (size_t)row * C_CH);
    float v[12];
    float m = -1e30f;
    for (int j = 0; j < 12; j++) {
        v[j] = bf2f(p[j * 64 + lane]);
        m = fmaxf(m, v[j]);
    }
    for (int off = 32; off; off >>= 1) m = fmaxf(m, __shfl_xor(m, off, 64));
    float s = 0.f;
    for (int j = 0; j < 12; j++) { v[j] = __expf(v[j] - m); s += v[j]; }
    for (int off = 32; off; off >>= 1) s += __shfl_xor(s, off, 64);
    float inv = 1.0f / s;
    for (int j = 0; j < 12; j++) p[j * 64 + lane] = f2bf(v[j] * inv);
}

// ---------------- NT GEMM: C[m,n] = scale * sum_k A[m,k]*B[n,k] (+bias/res) ----------------
// A: [M x K] row-major (rows at stride K), B: [N x K] row-major.
// Tile 128x128, BK=64, 4 waves each owning 64x64. global_load_lds staging with
// XOR-swizzled source so ds_read_b128 frag reads are ~conflict-free.
template<int OUT_F32>
__global__ __launch_bounds__(256, 2) void gemm_nt_kernel(
    const __hip_bfloat16* __restrict__ A, long sA,
    const __hip_bfloat16* __restrict__ B, long sB,
    void* __restrict__ Cout, long sC, int ldc,
    int K, float scale,
    const float* __restrict__ bias_row,
    const float* __restrict__ bias_col,
    const float* __restrict__ residual, long sR)
{
    __shared__ __hip_bfloat16 ldsA[128 * 64];
    __shared__ __hip_bfloat16 ldsB[128 * 64];
    const int t  = threadIdx.x;
    const int b  = blockIdx.z;
    const int m0 = blockIdx.y * 128;
    const int n0 = blockIdx.x * 128;
    const int lane = t & 63;
    const int wid  = t >> 6;
    const int wm = wid >> 1, wn = wid & 1;
    const int lrow = lane & 15, lk = lane >> 4;

    // staging: chunk idx = r*256 + t -> row = idx/8, chunk = idx%8 (16B chunks)
    const int srow   = t >> 3;                       // + r*32
    const int schunk = t & 7;
    const int kphys  = (schunk ^ (srow & 7)) * 8;    // element offset in [0,64)

    const __hip_bfloat16* aBase = A + (size_t)b * sA + (size_t)(m0 + srow) * K + kphys;
    const __hip_bfloat16* bBase = B + (size_t)b * sB + (size_t)(n0 + srow) * K + kphys;
    const int ldsDst = (t & ~63) * 8;                // wave-uniform elem offset; +r*2048

    f32x4 acc[4][4] = {};

    const int nk = K >> 6;
    for (int kt = 0; kt < nk; kt++) {
        __syncthreads();
        const __hip_bfloat16* ak = aBase + (size_t)kt * 64;
        const __hip_bfloat16* bk = bBase + (size_t)kt * 64;
        for (int r = 0; r < 4; r++)
            load_lds16(ak + (size_t)r * 32 * K, &ldsA[ldsDst + r * 2048]);
        for (int r = 0; r < 4; r++)
            load_lds16(bk + (size_t)r * 32 * K, &ldsB[ldsDst + r * 2048]);
        __syncthreads();
        for (int h = 0; h < 2; h++) {
            bf16x8 af[4], bfr[4];
            const int lc = h * 4 + lk;
            for (int i = 0; i < 4; i++) {
                int row = wm * 64 + i * 16 + lrow;
                int pc = lc ^ (row & 7);
                af[i] = *(const bf16x8*)&ldsA[row * 64 + pc * 8];
            }
            for (int i = 0; i < 4; i++) {
                int col = wn * 64 + i * 16 + lrow;
                int pc = lc ^ (col & 7);
                bfr[i] = *(const bf16x8*)&ldsB[col * 64 + pc * 8];
            }
            for (int i = 0; i < 4; i++)
                for (int j = 0; j < 4; j++)
                    acc[i][j] = __builtin_amdgcn_mfma_f32_16x16x32_bf16(
                        af[i], bfr[j], acc[i][j], 0, 0, 0);
        }
    }

    __hip_bfloat16* outB = (__hip_bfloat16*)Cout;
    float* outF = (float*)Cout;
    for (int i = 0; i < 4; i++)
        for (int j = 0; j < 4; j++) {
            int row = m0 + wm * 64 + i * 16 + lk * 4;
            int col = n0 + wn * 64 + j * 16 + lrow;
            f32x4 a = acc[i][j];
            for (int r = 0; r < 4; r++) {
                int rr = row + r;
                float v = a[r] * scale;
                if (bias_row) v += bias_row[rr];
                if (bias_col) v += bias_col[col];
                if (residual) v += residual[(size_t)b * sR + (size_t)rr * ldc + col];
                size_t off = (size_t)b * sC + (size_t)rr * ldc + col;
                if (OUT_F32) outF[off] = v;
                else         outB[off] = __float2bfloat16(v);
            }
        }
}

extern "C" void kernel_launch(void* const* d_in, const int* in_sizes, int n_in,
                              void* d_out, int out_size, void* d_ws, size_t ws_size,
                              hipStream_t stream) {
    const float* x     = (const float*)d_in[0];
    const float* gamma = (const float*)d_in[1];
    const float* beta  = (const float*)d_in[2];
    const float* w_qkv = (const float*)d_in[3];
    const float* b_qkv = (const float*)d_in[4];
    const float* w_out = (const float*)d_in[5];
    const float* b_out = (const float*)d_in[6];

    char* ws = (char*)d_ws;
    size_t off = 0;
    auto alloc = [&](size_t bytes) {
        void* p = ws + off;
        off += (bytes + 255) & ~(size_t)255;
        return p;
    };
    __hip_bfloat16* xnT   = (__hip_bfloat16*)alloc((size_t)BATCH * HW * C_CH * 2);
    __hip_bfloat16* wqkvB = (__hip_bfloat16*)alloc((size_t)3 * C_CH * C_CH * 2);
    __hip_bfloat16* woutB = (__hip_bfloat16*)alloc((size_t)C_CH * C_CH * 2);
    __hip_bfloat16* qk    = (__hip_bfloat16*)alloc((size_t)BATCH * 2 * C_CH * HW * 2);
    __hip_bfloat16* vT    = (__hip_bfloat16*)alloc((size_t)BATCH * HW * C_CH * 2);
    __hip_bfloat16* att   = (__hip_bfloat16*)alloc((size_t)BATCH * C_CH * C_CH * 2);
    __hip_bfloat16* outT  = (__hip_bfloat16*)alloc((size_t)BATCH * HW * C_CH * 2);
    float* stats          = (float*)alloc((size_t)BATCH * NG * 2 * 4);

    // 1) cast weights to bf16
    {
        int n4 = (3 * C_CH * C_CH) / 4;
        cast_bf16_kernel<<<(n4 + 255) / 256, 256, 0, stream>>>(
            (const float4*)w_qkv, (ushort4*)wqkvB, n4);
        int n4b = (C_CH * C_CH) / 4;
        cast_bf16_kernel<<<(n4b + 255) / 256, 256, 0, stream>>>(
            (const float4*)w_out, (ushort4*)woutB, n4b);
    }
    // 2) GroupNorm stats + normalize/transpose
    gn_stats_kernel<<<BATCH * NG, 256, 0, stream>>>(x, stats);
    gn_norm_kernel<<<dim3(HW / 64, BATCH), 256, 0, stream>>>(x, stats, gamma, beta, xnT);

    // 3) GEMM1a: qk[b,o,p] o<1536  (M=1536,N=1024,K=768)
    gemm_nt_kernel<0><<<dim3(HW / 128, 1536 / 128, BATCH), 256, 0, stream>>>(
        wqkvB, 0, xnT, (long)HW * C_CH, qk, (long)2 * C_CH * HW, HW,
        C_CH, 1.0f, b_qkv, nullptr, nullptr, 0);

    // 4) GEMM1b: v_T[b,p,j] (M=1024,N=768,K=768)
    gemm_nt_kernel<0><<<dim3(C_CH / 128, HW / 128, BATCH), 256, 0, stream>>>(
        xnT, (long)HW * C_CH, wqkvB + (size_t)2 * C_CH * C_CH, 0, vT, (long)HW * C_CH, C_CH,
        C_CH, 1.0f, nullptr, b_qkv + 2 * C_CH, nullptr, 0);

    // 5) GEMM2: att[b,i,j] = q.k^T * hw^-0.5  (M=768,N=768,K=1024)
    gemm_nt_kernel<0><<<dim3(C_CH / 128, C_CH / 128, BATCH), 256, 0, stream>>>(
        qk, (long)2 * C_CH * HW, qk + (size_t)C_CH * HW, (long)2 * C_CH * HW,
        att, (long)C_CH * C_CH, C_CH,
        HW, 1.0f / 32.0f, nullptr, nullptr, nullptr, 0);

    // 6) softmax rows
    softmax_kernel<<<(BATCH * C_CH) / 4, 256, 0, stream>>>(att);

    // 7) GEMM3: out_T[b,p,i] = v_T . att^T  (M=1024,N=768,K=768)
    gemm_nt_kernel<0><<<dim3(C_CH / 128, HW / 128, BATCH), 256, 0, stream>>>(
        vT, (long)HW * C_CH, att, (long)C_CH * C_CH, outT, (long)HW * C_CH, C_CH,
        C_CH, 1.0f, nullptr, nullptr, nullptr, 0);

    // 8) GEMM4: out[b,o,p] = w_out . out_T^T + b_out + x  (M=768,N=1024,K=768), f32 out
    gemm_nt_kernel<1><<<dim3(HW / 128, C_CH / 128, BATCH), 256, 0, stream>>>(
        woutB, 0, outT, (long)HW * C_CH, (float*)d_out, (long)C_CH * HW, HW,
        C_CH, 1.0f, b_out, nullptr, x, (long)C_CH * HW);
}